// Round 2
// baseline (2808.894 us; speedup 1.0000x reference)
//
#include <hip/hip_runtime.h>

#define T_SEQ 2048
#define HDIM  128
#define GDIM  512
#define BATCH 256

typedef _Float16 f16;
typedef _Float16 f16x2 __attribute__((ext_vector_type(2)));
typedef _Float16 f16x8 __attribute__((ext_vector_type(8)));

#if __has_builtin(__builtin_amdgcn_fdot2)
__device__ __forceinline__ float dot2(f16x2 a, f16x2 b, float c) {
    return __builtin_amdgcn_fdot2(a, b, c, false);
}
#else
__device__ __forceinline__ float dot2(f16x2 a, f16x2 b, float c) {
    return c + (float)a[0] * (float)b[0] + (float)a[1] * (float)b[1];
}
#endif

__device__ __forceinline__ f16x2 mk2(float a, float b) {
    f16x2 r; r[0] = (f16)a; r[1] = (f16)b; return r;
}
// pair m (0..3) of an f16x8 — one VGPR after inlining, feeds v_dot2 directly
__device__ __forceinline__ f16x2 pr(f16x8 v, int m) {
    f16x2 r; r[0] = v[2 * m]; r[1] = v[2 * m + 1]; return r;
}

__device__ __forceinline__ float sigm(float x) {
    return __builtin_amdgcn_rcpf(1.0f + __expf(-x));
}
// tanh(x) = 1 - 2/(e^{2x}+1); overflow -> rcp(inf)=0 -> exact +/-1 saturation
__device__ __forceinline__ float tanh_fast(float x) {
    float e = __expf(2.0f * x);
    return 1.0f - 2.0f * __builtin_amdgcn_rcpf(e + 1.0f);
}

// One block per batch element, 512 threads.
// Thread t owns PyTorch gate-row  row = (t&3)*128 + (t>>2)  of W_hh_l0,
// W_ih_l1, W_hh_l1 -- ALL in registers (192 f16x2). After the dot phase the
// 4 gates of unit u = t>>2 sit in 4 adjacent lanes of one wave: gather with
// __shfl, compute the cell update redundantly in all 4 lanes (no extra
// barrier, no idle-wave update phase). h state double-buffered in LDS ->
// ONE __syncthreads per step. Layers software-pipelined: iter i does
// layer0 step i and layer1 step i-1 (both read the same h0 generation).
__global__ __launch_bounds__(512, 1)   // arg2=1: 256-VGPR cap (arg2=2 capped at 128 -> spills, round 1)
void lstm_fused(const float* __restrict__ x,
                const float* __restrict__ Wih0,
                const float* __restrict__ Whh0,
                const float* __restrict__ bih0,
                const float* __restrict__ bhh0,
                const float* __restrict__ Wih1,
                const float* __restrict__ Whh1,
                const float* __restrict__ bih1,
                const float* __restrict__ bhh1,
                const float* __restrict__ Wfc,
                const float* __restrict__ bfc,
                float* __restrict__ out)
{
    __shared__ __align__(16) float xs[T_SEQ];      // whole x[b,:] (8 KB)
    __shared__ __align__(16) f16   h0b[2][HDIM];   // ping-pong h0 (f16)
    __shared__ __align__(16) f16   h1b[2][HDIM];   // ping-pong h1 (f16)
    __shared__ float ysum[8];

    const int t    = threadIdx.x;
    const int b    = blockIdx.x;
    const int gate = t & 3;
    const int u    = t >> 2;               // unit 0..127
    const int row  = gate * HDIM + u;      // PyTorch gate-major row index

    // stage the input sequence (coalesced)
    ((float4*)xs)[t] = ((const float4*)(x + (size_t)b * T_SEQ))[t];

    // ---- per-thread weights -> registers, f16-packed (192 VGPRs) ----
    f16x2 w0[64];  // W_hh_l0[row, :]
    f16x2 wi[64];  // W_ih_l1[row, :]
    f16x2 wl[64];  // W_hh_l1[row, :]
    {
        const float4* p0 = (const float4*)(Whh0 + (size_t)row * HDIM);
        const float4* p1 = (const float4*)(Wih1 + (size_t)row * HDIM);
        const float4* p2 = (const float4*)(Whh1 + (size_t)row * HDIM);
#pragma unroll
        for (int c = 0; c < 32; ++c) {
            float4 v = p0[c];
            w0[2 * c] = mk2(v.x, v.y); w0[2 * c + 1] = mk2(v.z, v.w);
        }
#pragma unroll
        for (int c = 0; c < 32; ++c) {
            float4 v = p1[c];
            wi[2 * c] = mk2(v.x, v.y); wi[2 * c + 1] = mk2(v.z, v.w);
        }
#pragma unroll
        for (int c = 0; c < 32; ++c) {
            float4 v = p2[c];
            wl[2 * c] = mk2(v.x, v.y); wl[2 * c + 1] = mk2(v.z, v.w);
        }
    }
    const float wx0   = Wih0[row];          // W_ih_l0 is [512,1]
    const float bias0 = bih0[row] + bhh0[row];
    const float bias1 = bih1[row] + bhh1[row];

    if (t < HDIM) { h0b[0][t] = (f16)0.f; h1b[0][t] = (f16)0.f; }
    float c0r = 0.f, c1r = 0.f;      // cell states (replicated in lane group)
    float h0fin = 0.f, h1fin = 0.f;  // last h values (for h_n output)
    __syncthreads();

    const int lb = (t & 63) & ~3;    // group base lane within the wave

    for (int i = 0; i <= T_SEQ; ++i) {
        const int p = i & 1, q = p ^ 1;
        const f16x8* h0p = (const f16x8*)h0b[p];
        const f16x8* h1p = (const f16x8*)h1b[p];

        // ---- dot phase: 192 v_dot2, 2 chains per accumulator for ILP ----
        float a0a = (i < T_SEQ ? xs[i] : 0.f) * wx0 + bias0, a0b = 0.f;
        float a1a = bias1, a1b = 0.f;
#pragma unroll
        for (int c = 0; c < 16; c += 2) {
            f16x8 ha = h0p[c], hb = h0p[c + 1];
#pragma unroll
            for (int m = 0; m < 4; ++m) {
                a0a = dot2(w0[4 * c + m],     pr(ha, m), a0a);
                a1a = dot2(wi[4 * c + m],     pr(ha, m), a1a);
                a0b = dot2(w0[4 * c + 4 + m], pr(hb, m), a0b);
                a1b = dot2(wi[4 * c + 4 + m], pr(hb, m), a1b);
            }
        }
#pragma unroll
        for (int c = 0; c < 16; c += 2) {
            f16x8 ha = h1p[c], hb = h1p[c + 1];
#pragma unroll
            for (int m = 0; m < 4; ++m) {
                a1a = dot2(wl[4 * c + m],     pr(ha, m), a1a);
                a1b = dot2(wl[4 * c + 4 + m], pr(hb, m), a1b);
            }
        }
        const float a0 = a0a + a0b;
        const float a1 = a1a + a1b;

        // ---- gather this unit's 4 gates from adjacent lanes ----
        float gi0 = __shfl(a0, lb + 0), gf0 = __shfl(a0, lb + 1);
        float gg0 = __shfl(a0, lb + 2), go0 = __shfl(a0, lb + 3);
        float gi1 = __shfl(a1, lb + 0), gf1 = __shfl(a1, lb + 1);
        float gg1 = __shfl(a1, lb + 2), go1 = __shfl(a1, lb + 3);

        // ---- cell updates, replicated across the 4 lanes of the group ----
        if (i < T_SEQ) {
            c0r   = sigm(gf0) * c0r + sigm(gi0) * tanh_fast(gg0);
            h0fin = sigm(go0) * tanh_fast(c0r);
            if (gate == 0) h0b[q][u] = (f16)h0fin;
        }
        if (i >= 1) {
            c1r   = sigm(gf1) * c1r + sigm(gi1) * tanh_fast(gg1);
            h1fin = sigm(go1) * tanh_fast(c1r);
            if (gate == 0) h1b[q][u] = (f16)h1fin;
        } else if (gate == 0) {
            h1b[q][u] = (f16)0.f;   // h1 state still zero when i==0
        }
        __syncthreads();
    }

    // ---- outputs: out = [ y(256) | h_n(2*256*128) | c_n(2*256*128) ] ----
    float* hn = out + BATCH;
    float* cn = out + BATCH + 2 * BATCH * HDIM;
    if (gate == 0) {
        hn[(size_t)b * HDIM + u] = h0fin;
        cn[(size_t)b * HDIM + u] = c0r;
        hn[BATCH * HDIM + (size_t)b * HDIM + u] = h1fin;
        cn[BATCH * HDIM + (size_t)b * HDIM + u] = c1r;
    }
    // y[b] = h1_final . W_fc + b_fc  (block reduction from registers)
    float part = (gate == 0) ? h1fin * Wfc[u] : 0.f;
#pragma unroll
    for (int o = 32; o >= 1; o >>= 1) part += __shfl_xor(part, o);
    if ((t & 63) == 0) ysum[t >> 6] = part;
    __syncthreads();
    if (t == 0) {
        float s = 0.f;
#pragma unroll
        for (int w = 0; w < 8; ++w) s += ysum[w];
        out[b] = s + bfc[0];
    }
}

extern "C" void kernel_launch(void* const* d_in, const int* in_sizes, int n_in,
                              void* d_out, int out_size, void* d_ws, size_t ws_size,
                              hipStream_t stream) {
    const float* x    = (const float*)d_in[0];
    const float* Wih0 = (const float*)d_in[1];
    const float* Whh0 = (const float*)d_in[2];
    const float* bih0 = (const float*)d_in[3];
    const float* bhh0 = (const float*)d_in[4];
    const float* Wih1 = (const float*)d_in[5];
    const float* Whh1 = (const float*)d_in[6];
    const float* bih1 = (const float*)d_in[7];
    const float* bhh1 = (const float*)d_in[8];
    const float* Wfc  = (const float*)d_in[9];
    const float* bfc  = (const float*)d_in[10];
    lstm_fused<<<BATCH, 512, 0, stream>>>(x, Wih0, Whh0, bih0, bhh0,
                                          Wih1, Whh1, bih1, bhh1,
                                          Wfc, bfc, (float*)d_out);
}